// Round 17
// baseline (237.179 us; speedup 1.0000x reference)
//
#include <hip/hip_runtime.h>

typedef unsigned short u16;
typedef __attribute__((ext_vector_type(8))) short bf16x8;
typedef __attribute__((ext_vector_type(4))) float f32x4;
typedef __attribute__((ext_vector_type(4))) u16 u16x4;

#define T_TOK 16384
#define D_DIM 1024
#define NE 8
#define MAXP 33792   // max padded compact rows: 2*T + 8*128

__device__ __forceinline__ u16 f2bf(float f) {
  union { float f; unsigned int u; } c; c.f = f;
  unsigned int u = c.u;
  u += 0x7fffu + ((u >> 16) & 1u);   // round-to-nearest-even
  return (u16)(u >> 16);
}

__device__ __forceinline__ float bf2f(u16 v) {
  union { unsigned int u; float f; } c; c.u = ((unsigned int)v) << 16;
  return c.f;
}

__device__ __forceinline__ float gelu_exact(float u) {
  return 0.5f * u * (1.0f + erff(u * 0.70710678118654752f));
}

__device__ __forceinline__ void gld16(const void* g, void* l) {
  __builtin_amdgcn_global_load_lds(
      (const __attribute__((address_space(1))) unsigned int*)g,
      (__attribute__((address_space(3))) unsigned int*)l, 16, 0, 0);
}

// ---- XOR-swizzle helpers (rule #21: linear gld16 dest + pre-swizzled global
// source col (col16 ^= row&7) + same XOR on fragment reads) -----------------

// Stage a 128-row x 64-col bf16 tile, swizzled source. g0 = tile origin.
__device__ __forceinline__ void stage_tile_swz(u16* lds, const char* g0, size_t stride,
                                               int wid, int lane) {
  const int rg = lane >> 3;                     // row&7 within each 8-row group
  const int cs = ((lane & 7) ^ rg) * 16;        // swizzled col byte
  const char* g = g0 + (size_t)(wid * 8 + rg) * stride + cs;
  char* l = (char*)lds + wid * 1024;            // linear dest; HW adds lane*16
  #pragma unroll
  for (int c = 0; c < 4; ++c)
    gld16(g + (size_t)(32 * c) * stride, l + c * 4096);
}

// swizzled fragment read: row stride 128 B
__device__ __forceinline__ bf16x8 rd_swz(const u16* lds, int row, int colu16) {
  const int byte = (row * 128 + colu16 * 2) ^ ((row & 7) << 4);
  return *(const bf16x8*)((const char*)lds + byte);
}

// swizzled fragment read/write: row stride 512 B (h tile, pure-LDS swizzle)
__device__ __forceinline__ bf16x8 rd_swz512(const u16* lds, int row, int colu16) {
  const int byte = (row * 512 + colu16 * 2) ^ ((row & 7) << 4);
  return *(const bf16x8*)((const char*)lds + byte);
}
__device__ __forceinline__ void wr_swz512(u16* lds, int row, int colu16, u16 v) {
  const int byte = (row * 512 + colu16 * 2) ^ ((row & 7) << 4);
  *(u16*)((char*)lds + byte) = v;
}

// ---- non-swizzled stagers used by gating (64-B-row tiles, left untouched) ----
__device__ __forceinline__ void stage_b64x32(u16* lds, const u16* mat, int rowbase,
                                             int k0, int wid, int lane) {
  const int row = wid * 16 + (lane >> 2);
  const char* g = (const char*)(mat + (size_t)(rowbase + row) * 1024 + k0 + (lane & 3) * 8);
  char* l = (char*)lds + wid * 1024;   // + lane*16 by HW
  gld16(g, l);
}

__device__ __forceinline__ void stage_b32(u16* lds, const u16* mat, int rowbase,
                                          int k0, int wid, int lane) {
  const char* g0 = (const char*)(mat + (size_t)rowbase * 1024 + k0);
  #pragma unroll
  for (int c = 0; c < 2; ++c) {
    const int row = c * 64 + wid * 16 + (lane >> 2);
    const char* g = g0 + (size_t)row * 2048 + (size_t)((lane & 3) * 16);
    char* l = (char*)lds + c * 4096 + wid * 1024;   // + lane*16 by HW
    gld16(g, l);
  }
}

// find expert owning padded compact row p0 (offs contiguous & 128-padded)
__device__ __forceinline__ int find_expert(const int* offs, int p0) {
  int e = 0;
  #pragma unroll
  for (int q = 1; q < NE; ++q) if (p0 >= offs[q]) e = q;
  return e;
}

// ---------------- x -> hi/lo bf16 split (coalesced, one pass) ----------------
__global__ __launch_bounds__(256) void cvt_hilo_x_kernel(const float* __restrict__ x,
                                                         u16* __restrict__ xh,
                                                         u16* __restrict__ xl) {
  const int i = (blockIdx.x * 256 + threadIdx.x) * 4;
  float4 v = *(const float4*)(x + i);
  float vv[4] = {v.x, v.y, v.z, v.w};
  u16x4 h, l;
  u16 hh[4], ll[4];
  #pragma unroll
  for (int q = 0; q < 4; ++q) { hh[q] = f2bf(vv[q]); ll[q] = f2bf(vv[q] - bf2f(hh[q])); }
  h.x = hh[0]; h.y = hh[1]; h.z = hh[2]; h.w = hh[3];
  l.x = ll[0]; l.y = ll[1]; l.z = ll[2]; l.w = ll[3];
  *(u16x4*)(xh + i) = h;
  *(u16x4*)(xl + i) = l;
}

// ---------------- tiled transpose+convert: in[e][R][C] f32 -> out[e][C][R] bf16 ----------------
__global__ __launch_bounds__(256) void transpose_cvt_kernel(const float* __restrict__ in,
                                                            u16* __restrict__ out,
                                                            int R, int C) {
  __shared__ u16 t[32][36];
  const int e = blockIdx.z;
  const int r0 = blockIdx.x * 32, c0 = blockIdx.y * 32;
  const int tid = threadIdx.x;
  {
    const int r = tid >> 3, cq = (tid & 7) * 4;
    float4 v = *(const float4*)(in + ((size_t)e * R + r0 + r) * C + c0 + cq);
    t[r][cq + 0] = f2bf(v.x); t[r][cq + 1] = f2bf(v.y);
    t[r][cq + 2] = f2bf(v.z); t[r][cq + 3] = f2bf(v.w);
  }
  __syncthreads();
  {
    const int c = tid >> 3, rq = (tid & 7) * 4;
    u16x4 o;
    o.x = t[rq + 0][c]; o.y = t[rq + 1][c]; o.z = t[rq + 2][c]; o.w = t[rq + 3][c];
    *(u16x4*)(out + ((size_t)e * C + c0 + c) * R + r0 + rq) = o;
  }
}

// ---------------- transpose+split-convert: in[R][C] f32 -> hi/lo [C][R] bf16 ----------------
__global__ __launch_bounds__(256) void transpose_hilo_kernel(const float* __restrict__ in,
                                                             u16* __restrict__ out_hi,
                                                             u16* __restrict__ out_lo,
                                                             int R, int C) {
  __shared__ u16 th[32][36];
  __shared__ u16 tl[32][36];
  const int r0 = blockIdx.x * 32, c0 = blockIdx.y * 32;
  const int tid = threadIdx.x;
  {
    const int r = tid >> 3, cq = (tid & 7) * 4;
    float4 v = *(const float4*)(in + (size_t)(r0 + r) * C + c0 + cq);
    float vv[4] = {v.x, v.y, v.z, v.w};
    #pragma unroll
    for (int i = 0; i < 4; ++i) {
      u16 h = f2bf(vv[i]);
      th[r][cq + i] = h;
      tl[r][cq + i] = f2bf(vv[i] - bf2f(h));
    }
  }
  __syncthreads();
  {
    const int c = tid >> 3, rq = (tid & 7) * 4;
    u16x4 oh, ol;
    oh.x = th[rq + 0][c]; oh.y = th[rq + 1][c]; oh.z = th[rq + 2][c]; oh.w = th[rq + 3][c];
    ol.x = tl[rq + 0][c]; ol.y = tl[rq + 1][c]; ol.z = tl[rq + 2][c]; ol.w = tl[rq + 3][c];
    *(u16x4*)(out_hi + (size_t)(c0 + c) * R + r0 + rq) = oh;
    *(u16x4*)(out_lo + (size_t)(c0 + c) * R + r0 + rq) = ol;
  }
}

// ---------------- gating GEMM1 via split-bf16 MFMA (3-term), pure gld16 staging ----------------
__global__ __launch_bounds__(256) void gating_mfma_kernel(
    const u16* __restrict__ xh, const u16* __restrict__ xl,
    const u16* __restrict__ wg1t_hi, const u16* __restrict__ wg1t_lo,
    float* __restrict__ p_buf) {
  __shared__ u16 Ah[64 * 32], Al[64 * 32];
  __shared__ u16 Bh[128 * 32], Bl[128 * 32];
  const int tid = threadIdx.x, lane = tid & 63, wid = tid >> 6;
  const int t0 = blockIdx.x * 64, n0 = blockIdx.y * 128;
  const int kh = blockIdx.z, kbeg = kh * 512;
  const int wm = wid >> 1, wn = wid & 1;

  f32x4 acc[2][4];
  #pragma unroll
  for (int i = 0; i < 2; ++i)
    #pragma unroll
    for (int j = 0; j < 4; ++j) acc[i][j] = (f32x4){0.f, 0.f, 0.f, 0.f};

  for (int kt = 0; kt < 16; ++kt) {
    const int k0 = kbeg + kt * 32;
    __syncthreads();
    stage_b64x32(Ah, xh, t0, k0, wid, lane);
    stage_b64x32(Al, xl, t0, k0, wid, lane);
    stage_b32(Bh, wg1t_hi, n0, k0, wid, lane);
    stage_b32(Bl, wg1t_lo, n0, k0, wid, lane);
    __syncthreads();
    const int r = lane & 15, ko = (lane >> 4) * 8;
    bf16x8 ah[2], al[2];
    #pragma unroll
    for (int mf = 0; mf < 2; ++mf) {
      const int ro = (wm * 32 + mf * 16 + r) * 32 + ko;
      ah[mf] = *(const bf16x8*)&Ah[ro];
      al[mf] = *(const bf16x8*)&Al[ro];
    }
    #pragma unroll
    for (int nf = 0; nf < 4; ++nf) {
      const int ro = (wn * 64 + nf * 16 + r) * 32 + ko;
      bf16x8 bh = *(const bf16x8*)&Bh[ro];
      bf16x8 bl = *(const bf16x8*)&Bl[ro];
      #pragma unroll
      for (int mf = 0; mf < 2; ++mf) {
        acc[mf][nf] = __builtin_amdgcn_mfma_f32_16x16x32_bf16(ah[mf], bh, acc[mf][nf], 0, 0, 0);
        acc[mf][nf] = __builtin_amdgcn_mfma_f32_16x16x32_bf16(ah[mf], bl, acc[mf][nf], 0, 0, 0);
        acc[mf][nf] = __builtin_amdgcn_mfma_f32_16x16x32_bf16(al[mf], bh, acc[mf][nf], 0, 0, 0);
      }
    }
  }

  #pragma unroll
  for (int mf = 0; mf < 2; ++mf)
    #pragma unroll
    for (int rr = 0; rr < 4; ++rr) {
      const int lt = wm * 32 + mf * 16 + ((lane >> 4) << 2) + rr;
      #pragma unroll
      for (int nf = 0; nf < 4; ++nf) {
        const int ln = wn * 64 + nf * 16 + (lane & 15);
        p_buf[((size_t)kh * T_TOK + t0 + lt) * 256 + n0 + ln] = acc[mf][nf][rr];
      }
    }
}

// ---------------- gating phase 2: sum 2 partials + bias + gelu + GEMM2 + softmax + top2 ----------------
__global__ __launch_bounds__(256) void gating_p2_kernel(
    const float* __restrict__ p_buf, const float* __restrict__ bg1,
    const float* __restrict__ wg2, const float* __restrict__ bg2,
    int* __restrict__ top_i, float2* __restrict__ top_g) {
  const int tid = threadIdx.x;
  const int tn = tid & 31, tm = tid >> 5;
  const int t0 = blockIdx.x * 32;

  float bb[8];
  {
    float4 ba = *(const float4*)&bg1[tn * 4];
    float4 bc = *(const float4*)&bg1[128 + tn * 4];
    bb[0] = ba.x; bb[1] = ba.y; bb[2] = ba.z; bb[3] = ba.w;
    bb[4] = bc.x; bb[5] = bc.y; bb[6] = bc.z; bb[7] = bc.w;
  }

  float hv[4][8];
  #pragma unroll
  for (int i = 0; i < 4; ++i) {
    const size_t t = t0 + tm * 4 + i;
    const float* pa = &p_buf[t * 256];
    const float* pb = &p_buf[((size_t)T_TOK + t) * 256];
    float4 a0 = *(const float4*)&pa[tn * 4];
    float4 a1 = *(const float4*)&pa[128 + tn * 4];
    float4 b0 = *(const float4*)&pb[tn * 4];
    float4 b1 = *(const float4*)&pb[128 + tn * 4];
    hv[i][0] = gelu_exact(a0.x + b0.x + bb[0]);
    hv[i][1] = gelu_exact(a0.y + b0.y + bb[1]);
    hv[i][2] = gelu_exact(a0.z + b0.z + bb[2]);
    hv[i][3] = gelu_exact(a0.w + b0.w + bb[3]);
    hv[i][4] = gelu_exact(a1.x + b1.x + bb[4]);
    hv[i][5] = gelu_exact(a1.y + b1.y + bb[5]);
    hv[i][6] = gelu_exact(a1.z + b1.z + bb[6]);
    hv[i][7] = gelu_exact(a1.w + b1.w + bb[7]);
  }

  float part[4][8];
  #pragma unroll
  for (int i = 0; i < 4; ++i)
    #pragma unroll
    for (int e = 0; e < 8; ++e) part[i][e] = 0.f;
  #pragma unroll
  for (int j = 0; j < 8; ++j) {
    const int col = (j < 4) ? (tn * 4 + j) : (128 + tn * 4 + (j - 4));
    float4 wa = *(const float4*)&wg2[col * 8];
    float4 wb = *(const float4*)&wg2[col * 8 + 4];
    float we[8] = {wa.x, wa.y, wa.z, wa.w, wb.x, wb.y, wb.z, wb.w};
    #pragma unroll
    for (int i = 0; i < 4; ++i)
      #pragma unroll
      for (int e = 0; e < 8; ++e) part[i][e] += hv[i][j] * we[e];
  }
  #pragma unroll
  for (int mask = 1; mask < 32; mask <<= 1)
    #pragma unroll
    for (int i = 0; i < 4; ++i)
      #pragma unroll
      for (int e = 0; e < 8; ++e) part[i][e] += __shfl_xor(part[i][e], mask);

  if (tn < 4) {
    float lg[8];
    #pragma unroll
    for (int i = 0; i < 4; ++i)
      if (tn == i) {
        #pragma unroll
        for (int e = 0; e < 8; ++e) lg[e] = part[i][e];
      }
    #pragma unroll
    for (int e = 0; e < 8; ++e) lg[e] += bg2[e];
    float m = lg[0];
    #pragma unroll
    for (int e = 1; e < 8; ++e) m = fmaxf(m, lg[e]);
    float ex[8], s = 0.f;
    #pragma unroll
    for (int e = 0; e < 8; ++e) { ex[e] = expf(lg[e] - m); s += ex[e]; }
    int i1 = 0;
    #pragma unroll
    for (int e = 1; e < 8; ++e) if (lg[e] > lg[i1]) i1 = e;   // strict >: lowest idx on tie
    int i2 = (i1 == 0) ? 1 : 0;
    #pragma unroll
    for (int e = 0; e < 8; ++e) if (e != i1 && lg[e] > lg[i2]) i2 = e;
    float inv = 1.f / s;
    const int t = t0 + tm * 4 + tn;
    top_i[t] = i1 | (i2 << 8);
    top_g[t] = make_float2(ex[i1] * inv, ex[i2] * inv);
  }
}

// ---------------- hist: per-256-token-chunk expert histogram (LDS atomics only) ----------------
__global__ __launch_bounds__(256) void hist_kernel(const int* __restrict__ top_i,
                                                   int* __restrict__ hist) {
  __shared__ int h[NE];
  const int tid = threadIdx.x;
  if (tid < NE) h[tid] = 0;
  __syncthreads();
  const int ti = top_i[blockIdx.x * 256 + tid];
  atomicAdd(&h[ti & 255], 1);
  atomicAdd(&h[ti >> 8], 1);
  __syncthreads();
  if (tid < NE) hist[blockIdx.x * NE + tid] = h[tid];
}

// ---------------- scan: totals, padded offsets, per-chunk bases (single block) ----------------
__global__ __launch_bounds__(64) void scan_kernel(const int* __restrict__ hist,
                                                  int* __restrict__ cnt,
                                                  int* __restrict__ offs,
                                                  int* __restrict__ cbase) {
  __shared__ int tot[NE], off_s[NE];
  const int tid = threadIdx.x;
  if (tid < NE) {
    int s = 0;
    for (int c = 0; c < 64; ++c) s += hist[c * NE + tid];
    tot[tid] = s; cnt[tid] = s;
  }
  __syncthreads();
  if (tid == 0) {
    int o = 0;
    #pragma unroll
    for (int e = 0; e < NE; ++e) { off_s[e] = o; o += (tot[e] + 127) & ~127; }
  }
  __syncthreads();
  if (tid < NE) {
    offs[tid] = off_s[tid];
    int r = off_s[tid];
    for (int c = 0; c < 64; ++c) { cbase[c * NE + tid] = r; r += hist[c * NE + tid]; }
  }
}

// ---------------- fill: scatter tokens into per-expert compact lists (LDS atomics) ----------------
__global__ __launch_bounds__(256) void fill_kernel(
    const int* __restrict__ top_i, const int* __restrict__ cbase,
    int* __restrict__ tok_list, int* __restrict__ pos1, int* __restrict__ pos2) {
  __shared__ int lcnt[NE];
  const int tid = threadIdx.x;
  if (tid < NE) lcnt[tid] = 0;
  __syncthreads();
  const int t = blockIdx.x * 256 + tid;
  const int ti = top_i[t];
  const int i1 = ti & 255, i2 = ti >> 8;
  const int r1 = atomicAdd(&lcnt[i1], 1);
  const int r2 = atomicAdd(&lcnt[i2], 1);
  const int p1 = cbase[blockIdx.x * NE + i1] + r1;
  const int p2 = cbase[blockIdx.x * NE + i2] + r2;
  tok_list[p1] = t; tok_list[p2] = t;
  pos1[t] = p1; pos2[t] = p2;
}

// ---------------- FUSED expert pass: o = (gelu(x[tok] @ W1e + b1) @ W2e + b2), bf16 ----------------
// grid (528): blockIdx.x = padded compact 64-row tile; expert via find_expert.
// Phase 1: h[64][256] = gelu(xb-gather @ w1t + b1) -> swizzled LDS (bf16).
// Phase 2: loop 8 n-tiles of 128: o[64][128] = h @ w2t + b2 -> o_c.
// All LDS tiles use the verified XOR swizzle (R16: conflicts -> 0).
__global__ __launch_bounds__(256) void fused_expert_kernel(
    const u16* __restrict__ xb, const u16* __restrict__ w1t,
    const u16* __restrict__ w2t, const float* __restrict__ b1,
    const float* __restrict__ b2, const int* __restrict__ tok_list,
    const int* __restrict__ cnt, const int* __restrict__ offs,
    u16* __restrict__ o_c) {
  __shared__ u16 AB[20480];          // 40 KB: As [0,4096), Bs [4096,20480)
  __shared__ u16 h_lds[64 * 256];    // 32 KB, swizzled 512B rows
  __shared__ float b1_s[256];
  u16* As = AB;
  u16* Bs = AB + 4096;
  u16* B2s = AB;                      // phase-2 B tile reuses front 16 KB

  const int tid = threadIdx.x, lane = tid & 63, wid = tid >> 6;
  const int base = blockIdx.x * 64;
  const int e = find_expert(offs, base);
  if (base >= offs[e] + ((cnt[e] + 127) & ~127)) return;
  const int wm = wid >> 1, wn = wid & 1;
  const int r = lane & 15, kq = (lane >> 4) * 8;

  b1_s[tid] = b1[e * 256 + tid];

  // token ids for this wave's two staged 8-row chunks
  int tk[2];
  #pragma unroll
  for (int c = 0; c < 2; ++c)
    tk[c] = tok_list[base + (wid * 2 + c) * 8 + (lane >> 3)];
  const int cb = ((lane & 7) ^ ((lane >> 3) & 7)) * 16;   // swizzled source col

  // ---- Phase 1: GEMM1, tile 64x256, wave (wm,wn) does 32x128 ----
  {
    f32x4 acc1[2][8];
    #pragma unroll
    for (int i = 0; i < 2; ++i)
      #pragma unroll
      for (int j = 0; j < 8; ++j) acc1[i][j] = (f32x4){0.f, 0.f, 0.f, 0.f};

    const char* Bb = (const char*)w1t + (size_t)e * 256 * 2048;
    for (int kt = 0; kt < 16; ++kt) {
      __syncthreads();
      {   // gather-stage A [64][64] swizzled
        char* l = (char*)As + wid * 2048;
        #pragma unroll
        for (int c = 0; c < 2; ++c)
          gld16((const char*)xb + (size_t)tk[c] * 2048 + kt * 128 + cb, l + c * 1024);
      }
      stage_tile_swz(Bs, Bb + kt * 128, 2048, wid, lane);                    // rows 0..127
      stage_tile_swz(Bs + 128 * 64, Bb + 128 * 2048 + kt * 128, 2048, wid, lane); // 128..255
      __syncthreads();
      #pragma unroll
      for (int ks = 0; ks < 2; ++ks) {
        const int col = ks * 32 + kq;
        bf16x8 a[2], b[8];
        #pragma unroll
        for (int mf = 0; mf < 2; ++mf)
          a[mf] = rd_swz(As, wm * 32 + mf * 16 + r, col);
        #pragma unroll
        for (int nf = 0; nf < 8; ++nf)
          b[nf] = rd_swz(Bs, wn * 128 + nf * 16 + r, col);
        #pragma unroll
        for (int mf = 0; mf < 2; ++mf)
          #pragma unroll
          for (int nf = 0; nf < 8; ++nf)
            acc1[mf][nf] = __builtin_amdgcn_mfma_f32_16x16x32_bf16(a[mf], b[nf], acc1[mf][nf], 0, 0, 0);
      }
    }
    // epilogue 1: bias + gelu -> swizzled h_lds (bf16)
    #pragma unroll
    for (int mf = 0; mf < 2; ++mf)
      #pragma unroll
      for (int rr = 0; rr < 4; ++rr) {
        const int row = wm * 32 + mf * 16 + ((lane >> 4) << 2) + rr;
        #pragma unroll
        for (int nf = 0; nf < 8; ++nf) {
          const int colc = wn * 128 + nf * 16 + (lane & 15);
          float u = acc1[mf][nf][rr] + b1_s[colc];
          wr_swz512(h_lds, row, colc, f2bf(gelu_exact(u)));
        }
      }
  }

  // ---- Phase 2: GEMM2, 8 n-tiles of 64x128; A = h_lds (512B-row swizzle) ----
  const char* Wb = (const char*)w2t + (size_t)e * D_DIM * 512;
  for (int nt = 0; nt < 8; ++nt) {
    const int n0 = nt * 128;
    f32x4 acc2[2][4];
    #pragma unroll
    for (int i = 0; i < 2; ++i)
      #pragma unroll
      for (int j = 0; j < 4; ++j) acc2[i][j] = (f32x4){0.f, 0.f, 0.f, 0.f};

    #pragma unroll 1
    for (int kt = 0; kt < 4; ++kt) {
      __syncthreads();   // protects B2s reuse (and, first iter, h_lds writes + phase-1 reads)
      stage_tile_swz(B2s, Wb + (size_t)n0 * 512 + kt * 128, 512, wid, lane);
      __syncthreads();
      #pragma unroll
      for (int ks = 0; ks < 2; ++ks) {
        const int col = ks * 32 + kq;
        bf16x8 a[2], b[4];
        #pragma unroll
        for (int mf = 0; mf < 2; ++mf)
          a[mf] = rd_swz512(h_lds, wm * 32 + mf * 16 + r, kt * 64 + col);
        #pragma unroll
        for (int nf = 0; nf < 4; ++nf)
          b[nf] = rd_swz(B2s, wn * 64 + nf * 16 + r, col);
        #pragma unroll
        for (int mf = 0; mf < 2; ++mf)
          #pragma unroll
          for (int nf = 0; nf < 4; ++nf)
            acc2[mf][nf] = __builtin_amdgcn_mfma_f32_16x16x32_bf16(a[mf], b[nf], acc2[mf][nf], 0, 0, 0);
      }
    }
    // epilogue 2: +b2, write o_c
    #pragma unroll
    for (int nf = 0; nf < 4; ++nf) {
      const int ln = wn * 64 + nf * 16 + (lane & 15);
      const float bv = b2[(size_t)e * 1024 + n0 + ln];
      #pragma unroll
      for (int mf = 0; mf < 2; ++mf)
        #pragma unroll
        for (int rr = 0; rr < 4; ++rr) {
          const int lt = wm * 32 + mf * 16 + ((lane >> 4) << 2) + rr;
          o_c[(size_t)(base + lt) * 1024 + n0 + ln] = f2bf(acc2[mf][nf][rr] + bv);
        }
    }
  }
}

// ---------------- gather: y[t] = g1*o[p1] + g2*o[p2] ----------------
__global__ __launch_bounds__(256) void gather_kernel(
    const u16* __restrict__ o_c, const int* __restrict__ pos1,
    const int* __restrict__ pos2, const float2* __restrict__ top_g,
    float* __restrict__ y) {
  const int t = blockIdx.x;
  const int p1 = pos1[t], p2 = pos2[t];
  const float2 g = top_g[t];
  const int c = threadIdx.x * 4;
  u16x4 a = *(const u16x4*)&o_c[(size_t)p1 * 1024 + c];
  u16x4 b = *(const u16x4*)&o_c[(size_t)p2 * 1024 + c];
  float4 o;
  o.x = g.x * bf2f(a.x) + g.y * bf2f(b.x);
  o.y = g.x * bf2f(a.y) + g.y * bf2f(b.y);
  o.z = g.x * bf2f(a.z) + g.y * bf2f(b.z);
  o.w = g.x * bf2f(a.w) + g.y * bf2f(b.w);
  *(float4*)&y[(size_t)t * 1024 + c] = o;
}

extern "C" void kernel_launch(void* const* d_in, const int* in_sizes, int n_in,
                              void* d_out, int out_size, void* d_ws, size_t ws_size,
                              hipStream_t stream) {
  (void)in_sizes; (void)n_in; (void)out_size; (void)ws_size;
  const float* x   = (const float*)d_in[0];
  const float* wg1 = (const float*)d_in[1];
  const float* bg1 = (const float*)d_in[2];
  const float* wg2 = (const float*)d_in[3];
  const float* bg2 = (const float*)d_in[4];
  const float* w1  = (const float*)d_in[5];
  const float* b1  = (const float*)d_in[6];
  const float* w2  = (const float*)d_in[7];
  const float* b2  = (const float*)d_in[8];
  float* y = (float*)d_out;

  char* ws = (char*)d_ws;
  u16* xb   = (u16*)(ws);                 // 33,554,432 B  (= x_hi; expert path input)
  u16* w1t  = (u16*)(ws + 33554432);      //  4,194,304 B
  u16* w2t  = (u16*)(ws + 37748736);      //  4,194,304 B
  char* M   = ws + 41943040;              // metadata block
  int*    cnt      = (int*)(M);                 // 32 B
  int*    offs     = (int*)(M + 64);            // 32 B
  int*    hist     = (int*)(M + 128);           // 2,048 B
  int*    cbase    = (int*)(M + 2304);          // 2,048 B
  int*    tok_list = (int*)(M + 4608);          // 135,168 B
  int*    top_i    = (int*)(M + 139776);        // 65,536 B
  float2* top_g    = (float2*)(M + 205312);     // 131,072 B
  int*    pos1     = (int*)(M + 336384);        // 65,536 B
  int*    pos2     = (int*)(M + 401920);        // 65,536 B
  u16* o_c = (u16*)(ws + 59768832);       // MAXP*1024*2 = 69,206,016 B (ends 128,974,848)
  // Aliased onto o_c region (all dead before fused_expert writes o_c):
  float* p_buf   = (float*)(ws + 59768832);          // [2][T][256] f32 = 33,554,432 B
  u16*   wg1t_hi = (u16*)(ws + 93323264);            // 524,288 B
  u16*   wg1t_lo = (u16*)(ws + 93847552);            // 524,288 B
  u16*   xl      = (u16*)(ws + 94371840);            // 33,554,432 B (ends 127,926,272)

  hipMemsetAsync(tok_list, 0, 135168, stream);  // pad slots -> token 0
  cvt_hilo_x_kernel<<<16384, 256, 0, stream>>>(x, xb, xl);
  transpose_cvt_kernel<<<dim3(32, 8, 8), 256, 0, stream>>>(w1, w1t, 1024, 256);
  transpose_cvt_kernel<<<dim3(8, 32, 8), 256, 0, stream>>>(w2, w2t, 256, 1024);
  transpose_hilo_kernel<<<dim3(32, 8), 256, 0, stream>>>(wg1, wg1t_hi, wg1t_lo, 1024, 256);
  gating_mfma_kernel<<<dim3(256, 2, 2), 256, 0, stream>>>(xb, xl, wg1t_hi, wg1t_lo, p_buf);
  gating_p2_kernel<<<512, 256, 0, stream>>>(p_buf, bg1, wg2, bg2, top_i, top_g);
  hist_kernel<<<64, 256, 0, stream>>>(top_i, hist);
  scan_kernel<<<1, 64, 0, stream>>>(hist, cnt, offs, cbase);
  fill_kernel<<<64, 256, 0, stream>>>(top_i, cbase, tok_list, pos1, pos2);
  fused_expert_kernel<<<528, 256, 0, stream>>>(xb, w1t, w2t, b1, b2, tok_list, cnt, offs, o_c);
  gather_kernel<<<16384, 256, 0, stream>>>(o_c, pos1, pos2, top_g, y);
}

// Round 18
// 191.528 us; speedup vs baseline: 1.2384x; 1.2384x over previous
//
#include <hip/hip_runtime.h>

typedef unsigned short u16;
typedef __attribute__((ext_vector_type(8))) short bf16x8;
typedef __attribute__((ext_vector_type(4))) float f32x4;
typedef __attribute__((ext_vector_type(4))) u16 u16x4;

#define T_TOK 16384
#define D_DIM 1024
#define NE 8
#define MAXP 33792   // max padded compact rows: 2*T + 8*128

__device__ __forceinline__ u16 f2bf(float f) {
  union { float f; unsigned int u; } c; c.f = f;
  unsigned int u = c.u;
  u += 0x7fffu + ((u >> 16) & 1u);   // round-to-nearest-even
  return (u16)(u >> 16);
}

__device__ __forceinline__ float bf2f(u16 v) {
  union { unsigned int u; float f; } c; c.u = ((unsigned int)v) << 16;
  return c.f;
}

__device__ __forceinline__ float gelu_exact(float u) {
  return 0.5f * u * (1.0f + erff(u * 0.70710678118654752f));
}

__device__ __forceinline__ void gld16(const void* g, void* l) {
  __builtin_amdgcn_global_load_lds(
      (const __attribute__((address_space(1))) unsigned int*)g,
      (__attribute__((address_space(3))) unsigned int*)l, 16, 0, 0);
}

// ---- XOR-swizzle helpers (rule #21: linear gld16 dest + pre-swizzled global
// source col (col16 ^= row&7) + same XOR on fragment reads). Verified R16:
// SQ_LDS_BANK_CONFLICT -> 0. -------------------------------------------------

// Stage a 128-row x 64-col bf16 tile, swizzled source, 4 waves. g0 = tile origin.
__device__ __forceinline__ void stage_tile_swz(u16* lds, const char* g0, size_t stride,
                                               int wid, int lane) {
  const int rg = lane >> 3;                     // row&7 within each 8-row group
  const int cs = ((lane & 7) ^ rg) * 16;        // swizzled col byte
  const char* g = g0 + (size_t)(wid * 8 + rg) * stride + cs;
  char* l = (char*)lds + wid * 1024;            // linear dest; HW adds lane*16
  #pragma unroll
  for (int c = 0; c < 4; ++c)
    gld16(g + (size_t)(32 * c) * stride, l + c * 4096);
}

// 8-wave: stage a 128-row x 64-col tile (wave w -> rows w*16..+15)
__device__ __forceinline__ void stage_a128_8w(u16* lds, const char* g0, size_t stride,
                                              int wid, int lane) {
  const int rg = lane >> 3;
  const int cs = ((lane & 7) ^ rg) * 16;
  const char* g = g0 + (size_t)(wid * 16 + rg) * stride + cs;
  char* l = (char*)lds + wid * 2048;
  gld16(g, l);
  gld16(g + (size_t)8 * stride, l + 1024);      // (rg+8)&7 == rg: swizzle consistent
}

// 8-wave: stage a 256-row x 64-col tile (wave w -> rows w*32..+31)
__device__ __forceinline__ void stage_b256_8w(u16* lds, const char* g0, size_t stride,
                                              int wid, int lane) {
  const int rg = lane >> 3;
  const int cs = ((lane & 7) ^ rg) * 16;
  const char* g = g0 + (size_t)(wid * 32 + rg) * stride + cs;
  char* l = (char*)lds + wid * 4096;
  #pragma unroll
  for (int c = 0; c < 4; ++c)
    gld16(g + (size_t)(8 * c) * stride, l + c * 1024);
}

// swizzled fragment read: row stride 128 B
__device__ __forceinline__ bf16x8 rd_swz(const u16* lds, int row, int colu16) {
  const int byte = (row * 128 + colu16 * 2) ^ ((row & 7) << 4);
  return *(const bf16x8*)((const char*)lds + byte);
}

// 128x128 tile mma (4 waves 2x2, acc[4][4]), swizzled reads
__device__ __forceinline__ void mma_step_swz(const u16* As, const u16* Bs, f32x4 acc[4][4],
                                             int wm, int wn, int lane) {
  const int r = lane & 15, kq = (lane >> 4) * 8;
  #pragma unroll
  for (int ks = 0; ks < 2; ++ks) {
    const int col = ks * 32 + kq;
    bf16x8 a[4], b[4];
    #pragma unroll
    for (int mf = 0; mf < 4; ++mf)
      a[mf] = rd_swz(As, wm * 64 + mf * 16 + r, col);
    #pragma unroll
    for (int nf = 0; nf < 4; ++nf)
      b[nf] = rd_swz(Bs, wn * 64 + nf * 16 + r, col);
    #pragma unroll
    for (int mf = 0; mf < 4; ++mf)
      #pragma unroll
      for (int nf = 0; nf < 4; ++nf)
        acc[mf][nf] = __builtin_amdgcn_mfma_f32_16x16x32_bf16(a[mf], b[nf], acc[mf][nf], 0, 0, 0);
  }
}

// 64x128 tile mma (4 waves 2x2, wave does 32x64, acc[2][4]), swizzled reads
__device__ __forceinline__ void mma_64x128_swz(const u16* As, const u16* Bs, f32x4 acc[2][4],
                                               int wm, int wn, int lane) {
  const int r = lane & 15, kq = (lane >> 4) * 8;
  #pragma unroll
  for (int ks = 0; ks < 2; ++ks) {
    const int col = ks * 32 + kq;
    bf16x8 a[2], b[4];
    #pragma unroll
    for (int mf = 0; mf < 2; ++mf)
      a[mf] = rd_swz(As, wm * 32 + mf * 16 + r, col);
    #pragma unroll
    for (int nf = 0; nf < 4; ++nf)
      b[nf] = rd_swz(Bs, wn * 64 + nf * 16 + r, col);
    #pragma unroll
    for (int mf = 0; mf < 2; ++mf)
      #pragma unroll
      for (int nf = 0; nf < 4; ++nf)
        acc[mf][nf] = __builtin_amdgcn_mfma_f32_16x16x32_bf16(a[mf], b[nf], acc[mf][nf], 0, 0, 0);
  }
}

// ---- non-swizzled stagers used by gating (64-B-row tiles, left untouched) ----
__device__ __forceinline__ void stage_b64x32(u16* lds, const u16* mat, int rowbase,
                                             int k0, int wid, int lane) {
  const int row = wid * 16 + (lane >> 2);
  const char* g = (const char*)(mat + (size_t)(rowbase + row) * 1024 + k0 + (lane & 3) * 8);
  char* l = (char*)lds + wid * 1024;   // + lane*16 by HW
  gld16(g, l);
}

__device__ __forceinline__ void stage_b32(u16* lds, const u16* mat, int rowbase,
                                          int k0, int wid, int lane) {
  const char* g0 = (const char*)(mat + (size_t)rowbase * 1024 + k0);
  #pragma unroll
  for (int c = 0; c < 2; ++c) {
    const int row = c * 64 + wid * 16 + (lane >> 2);
    const char* g = g0 + (size_t)row * 2048 + (size_t)((lane & 3) * 16);
    char* l = (char*)lds + c * 4096 + wid * 1024;   // + lane*16 by HW
    gld16(g, l);
  }
}

// find expert owning padded compact row p0 (offs contiguous & 128-padded)
__device__ __forceinline__ int find_expert(const int* offs, int p0) {
  int e = 0;
  #pragma unroll
  for (int q = 1; q < NE; ++q) if (p0 >= offs[q]) e = q;
  return e;
}

// ---------------- x -> hi/lo bf16 split (coalesced, one pass) ----------------
__global__ __launch_bounds__(256) void cvt_hilo_x_kernel(const float* __restrict__ x,
                                                         u16* __restrict__ xh,
                                                         u16* __restrict__ xl) {
  const int i = (blockIdx.x * 256 + threadIdx.x) * 4;
  float4 v = *(const float4*)(x + i);
  float vv[4] = {v.x, v.y, v.z, v.w};
  u16x4 h, l;
  u16 hh[4], ll[4];
  #pragma unroll
  for (int q = 0; q < 4; ++q) { hh[q] = f2bf(vv[q]); ll[q] = f2bf(vv[q] - bf2f(hh[q])); }
  h.x = hh[0]; h.y = hh[1]; h.z = hh[2]; h.w = hh[3];
  l.x = ll[0]; l.y = ll[1]; l.z = ll[2]; l.w = ll[3];
  *(u16x4*)(xh + i) = h;
  *(u16x4*)(xl + i) = l;
}

// ---------------- tiled transpose+convert: in[e][R][C] f32 -> out[e][C][R] bf16 ----------------
__global__ __launch_bounds__(256) void transpose_cvt_kernel(const float* __restrict__ in,
                                                            u16* __restrict__ out,
                                                            int R, int C) {
  __shared__ u16 t[32][36];
  const int e = blockIdx.z;
  const int r0 = blockIdx.x * 32, c0 = blockIdx.y * 32;
  const int tid = threadIdx.x;
  {
    const int r = tid >> 3, cq = (tid & 7) * 4;
    float4 v = *(const float4*)(in + ((size_t)e * R + r0 + r) * C + c0 + cq);
    t[r][cq + 0] = f2bf(v.x); t[r][cq + 1] = f2bf(v.y);
    t[r][cq + 2] = f2bf(v.z); t[r][cq + 3] = f2bf(v.w);
  }
  __syncthreads();
  {
    const int c = tid >> 3, rq = (tid & 7) * 4;
    u16x4 o;
    o.x = t[rq + 0][c]; o.y = t[rq + 1][c]; o.z = t[rq + 2][c]; o.w = t[rq + 3][c];
    *(u16x4*)(out + ((size_t)e * C + c0 + c) * R + r0 + rq) = o;
  }
}

// ---------------- transpose+split-convert: in[R][C] f32 -> hi/lo [C][R] bf16 ----------------
__global__ __launch_bounds__(256) void transpose_hilo_kernel(const float* __restrict__ in,
                                                             u16* __restrict__ out_hi,
                                                             u16* __restrict__ out_lo,
                                                             int R, int C) {
  __shared__ u16 th[32][36];
  __shared__ u16 tl[32][36];
  const int r0 = blockIdx.x * 32, c0 = blockIdx.y * 32;
  const int tid = threadIdx.x;
  {
    const int r = tid >> 3, cq = (tid & 7) * 4;
    float4 v = *(const float4*)(in + (size_t)(r0 + r) * C + c0 + cq);
    float vv[4] = {v.x, v.y, v.z, v.w};
    #pragma unroll
    for (int i = 0; i < 4; ++i) {
      u16 h = f2bf(vv[i]);
      th[r][cq + i] = h;
      tl[r][cq + i] = f2bf(vv[i] - bf2f(h));
    }
  }
  __syncthreads();
  {
    const int c = tid >> 3, rq = (tid & 7) * 4;
    u16x4 oh, ol;
    oh.x = th[rq + 0][c]; oh.y = th[rq + 1][c]; oh.z = th[rq + 2][c]; oh.w = th[rq + 3][c];
    ol.x = tl[rq + 0][c]; ol.y = tl[rq + 1][c]; ol.z = tl[rq + 2][c]; ol.w = tl[rq + 3][c];
    *(u16x4*)(out_hi + (size_t)(c0 + c) * R + r0 + rq) = oh;
    *(u16x4*)(out_lo + (size_t)(c0 + c) * R + r0 + rq) = ol;
  }
}

// ---------------- gating GEMM1 via split-bf16 MFMA (3-term), pure gld16 staging ----------------
__global__ __launch_bounds__(256) void gating_mfma_kernel(
    const u16* __restrict__ xh, const u16* __restrict__ xl,
    const u16* __restrict__ wg1t_hi, const u16* __restrict__ wg1t_lo,
    float* __restrict__ p_buf) {
  __shared__ u16 Ah[64 * 32], Al[64 * 32];
  __shared__ u16 Bh[128 * 32], Bl[128 * 32];
  const int tid = threadIdx.x, lane = tid & 63, wid = tid >> 6;
  const int t0 = blockIdx.x * 64, n0 = blockIdx.y * 128;
  const int kh = blockIdx.z, kbeg = kh * 512;
  const int wm = wid >> 1, wn = wid & 1;

  f32x4 acc[2][4];
  #pragma unroll
  for (int i = 0; i < 2; ++i)
    #pragma unroll
    for (int j = 0; j < 4; ++j) acc[i][j] = (f32x4){0.f, 0.f, 0.f, 0.f};

  for (int kt = 0; kt < 16; ++kt) {
    const int k0 = kbeg + kt * 32;
    __syncthreads();
    stage_b64x32(Ah, xh, t0, k0, wid, lane);
    stage_b64x32(Al, xl, t0, k0, wid, lane);
    stage_b32(Bh, wg1t_hi, n0, k0, wid, lane);
    stage_b32(Bl, wg1t_lo, n0, k0, wid, lane);
    __syncthreads();
    const int r = lane & 15, ko = (lane >> 4) * 8;
    bf16x8 ah[2], al[2];
    #pragma unroll
    for (int mf = 0; mf < 2; ++mf) {
      const int ro = (wm * 32 + mf * 16 + r) * 32 + ko;
      ah[mf] = *(const bf16x8*)&Ah[ro];
      al[mf] = *(const bf16x8*)&Al[ro];
    }
    #pragma unroll
    for (int nf = 0; nf < 4; ++nf) {
      const int ro = (wn * 64 + nf * 16 + r) * 32 + ko;
      bf16x8 bh = *(const bf16x8*)&Bh[ro];
      bf16x8 bl = *(const bf16x8*)&Bl[ro];
      #pragma unroll
      for (int mf = 0; mf < 2; ++mf) {
        acc[mf][nf] = __builtin_amdgcn_mfma_f32_16x16x32_bf16(ah[mf], bh, acc[mf][nf], 0, 0, 0);
        acc[mf][nf] = __builtin_amdgcn_mfma_f32_16x16x32_bf16(ah[mf], bl, acc[mf][nf], 0, 0, 0);
        acc[mf][nf] = __builtin_amdgcn_mfma_f32_16x16x32_bf16(al[mf], bh, acc[mf][nf], 0, 0, 0);
      }
    }
  }

  #pragma unroll
  for (int mf = 0; mf < 2; ++mf)
    #pragma unroll
    for (int rr = 0; rr < 4; ++rr) {
      const int lt = wm * 32 + mf * 16 + ((lane >> 4) << 2) + rr;
      #pragma unroll
      for (int nf = 0; nf < 4; ++nf) {
        const int ln = wn * 64 + nf * 16 + (lane & 15);
        p_buf[((size_t)kh * T_TOK + t0 + lt) * 256 + n0 + ln] = acc[mf][nf][rr];
      }
    }
}

// ---------------- gating phase 2: sum 2 partials + bias + gelu + GEMM2 + softmax + top2 ----------------
__global__ __launch_bounds__(256) void gating_p2_kernel(
    const float* __restrict__ p_buf, const float* __restrict__ bg1,
    const float* __restrict__ wg2, const float* __restrict__ bg2,
    int* __restrict__ top_i, float2* __restrict__ top_g) {
  const int tid = threadIdx.x;
  const int tn = tid & 31, tm = tid >> 5;
  const int t0 = blockIdx.x * 32;

  float bb[8];
  {
    float4 ba = *(const float4*)&bg1[tn * 4];
    float4 bc = *(const float4*)&bg1[128 + tn * 4];
    bb[0] = ba.x; bb[1] = ba.y; bb[2] = ba.z; bb[3] = ba.w;
    bb[4] = bc.x; bb[5] = bc.y; bb[6] = bc.z; bb[7] = bc.w;
  }

  float hv[4][8];
  #pragma unroll
  for (int i = 0; i < 4; ++i) {
    const size_t t = t0 + tm * 4 + i;
    const float* pa = &p_buf[t * 256];
    const float* pb = &p_buf[((size_t)T_TOK + t) * 256];
    float4 a0 = *(const float4*)&pa[tn * 4];
    float4 a1 = *(const float4*)&pa[128 + tn * 4];
    float4 b0 = *(const float4*)&pb[tn * 4];
    float4 b1 = *(const float4*)&pb[128 + tn * 4];
    hv[i][0] = gelu_exact(a0.x + b0.x + bb[0]);
    hv[i][1] = gelu_exact(a0.y + b0.y + bb[1]);
    hv[i][2] = gelu_exact(a0.z + b0.z + bb[2]);
    hv[i][3] = gelu_exact(a0.w + b0.w + bb[3]);
    hv[i][4] = gelu_exact(a1.x + b1.x + bb[4]);
    hv[i][5] = gelu_exact(a1.y + b1.y + bb[5]);
    hv[i][6] = gelu_exact(a1.z + b1.z + bb[6]);
    hv[i][7] = gelu_exact(a1.w + b1.w + bb[7]);
  }

  float part[4][8];
  #pragma unroll
  for (int i = 0; i < 4; ++i)
    #pragma unroll
    for (int e = 0; e < 8; ++e) part[i][e] = 0.f;
  #pragma unroll
  for (int j = 0; j < 8; ++j) {
    const int col = (j < 4) ? (tn * 4 + j) : (128 + tn * 4 + (j - 4));
    float4 wa = *(const float4*)&wg2[col * 8];
    float4 wb = *(const float4*)&wg2[col * 8 + 4];
    float we[8] = {wa.x, wa.y, wa.z, wa.w, wb.x, wb.y, wb.z, wb.w};
    #pragma unroll
    for (int i = 0; i < 4; ++i)
      #pragma unroll
      for (int e = 0; e < 8; ++e) part[i][e] += hv[i][j] * we[e];
  }
  #pragma unroll
  for (int mask = 1; mask < 32; mask <<= 1)
    #pragma unroll
    for (int i = 0; i < 4; ++i)
      #pragma unroll
      for (int e = 0; e < 8; ++e) part[i][e] += __shfl_xor(part[i][e], mask);

  if (tn < 4) {
    float lg[8];
    #pragma unroll
    for (int i = 0; i < 4; ++i)
      if (tn == i) {
        #pragma unroll
        for (int e = 0; e < 8; ++e) lg[e] = part[i][e];
      }
    #pragma unroll
    for (int e = 0; e < 8; ++e) lg[e] += bg2[e];
    float m = lg[0];
    #pragma unroll
    for (int e = 1; e < 8; ++e) m = fmaxf(m, lg[e]);
    float ex[8], s = 0.f;
    #pragma unroll
    for (int e = 0; e < 8; ++e) { ex[e] = expf(lg[e] - m); s += ex[e]; }
    int i1 = 0;
    #pragma unroll
    for (int e = 1; e < 8; ++e) if (lg[e] > lg[i1]) i1 = e;   // strict >: lowest idx on tie
    int i2 = (i1 == 0) ? 1 : 0;
    #pragma unroll
    for (int e = 0; e < 8; ++e) if (e != i1 && lg[e] > lg[i2]) i2 = e;
    float inv = 1.f / s;
    const int t = t0 + tm * 4 + tn;
    top_i[t] = i1 | (i2 << 8);
    top_g[t] = make_float2(ex[i1] * inv, ex[i2] * inv);
  }
}

// ---------------- hist: per-256-token-chunk expert histogram (LDS atomics only) ----------------
__global__ __launch_bounds__(256) void hist_kernel(const int* __restrict__ top_i,
                                                   int* __restrict__ hist) {
  __shared__ int h[NE];
  const int tid = threadIdx.x;
  if (tid < NE) h[tid] = 0;
  __syncthreads();
  const int ti = top_i[blockIdx.x * 256 + tid];
  atomicAdd(&h[ti & 255], 1);
  atomicAdd(&h[ti >> 8], 1);
  __syncthreads();
  if (tid < NE) hist[blockIdx.x * NE + tid] = h[tid];
}

// ---------------- scan: totals, padded offsets, per-chunk bases (single block) ----------------
__global__ __launch_bounds__(64) void scan_kernel(const int* __restrict__ hist,
                                                  int* __restrict__ cnt,
                                                  int* __restrict__ offs,
                                                  int* __restrict__ cbase) {
  __shared__ int tot[NE], off_s[NE];
  const int tid = threadIdx.x;
  if (tid < NE) {
    int s = 0;
    for (int c = 0; c < 64; ++c) s += hist[c * NE + tid];
    tot[tid] = s; cnt[tid] = s;
  }
  __syncthreads();
  if (tid == 0) {
    int o = 0;
    #pragma unroll
    for (int e = 0; e < NE; ++e) { off_s[e] = o; o += (tot[e] + 127) & ~127; }
  }
  __syncthreads();
  if (tid < NE) {
    offs[tid] = off_s[tid];
    int r = off_s[tid];
    for (int c = 0; c < 64; ++c) { cbase[c * NE + tid] = r; r += hist[c * NE + tid]; }
  }
}

// ---------------- fill: scatter tokens into per-expert compact lists (LDS atomics) ----------------
__global__ __launch_bounds__(256) void fill_kernel(
    const int* __restrict__ top_i, const int* __restrict__ cbase,
    int* __restrict__ tok_list, int* __restrict__ pos1, int* __restrict__ pos2) {
  __shared__ int lcnt[NE];
  const int tid = threadIdx.x;
  if (tid < NE) lcnt[tid] = 0;
  __syncthreads();
  const int t = blockIdx.x * 256 + tid;
  const int ti = top_i[t];
  const int i1 = ti & 255, i2 = ti >> 8;
  const int r1 = atomicAdd(&lcnt[i1], 1);
  const int r2 = atomicAdd(&lcnt[i2], 1);
  const int p1 = cbase[blockIdx.x * NE + i1] + r1;
  const int p2 = cbase[blockIdx.x * NE + i2] + r2;
  tok_list[p1] = t; tok_list[p2] = t;
  pos1[t] = p1; pos2[t] = p2;
}

// ---------------- pass A (compact, BM=64, swizzled LDS): h = gelu(x @ W1e + b1e) ----------------
// R16 form (proven): grid (256,2,8) + early-exit, single-buffered.
__global__ __launch_bounds__(256) void expert_h_kernel(
    const u16* __restrict__ xb, const u16* __restrict__ w1t,
    const float* __restrict__ b1, const int* __restrict__ tok_list,
    const int* __restrict__ cnt, const int* __restrict__ offs,
    u16* __restrict__ h_c) {
  __shared__ u16 As[64 * 64];
  __shared__ u16 Bs[128 * 64];
  __shared__ float b1_s[128];
  const int e = blockIdx.z;
  const int nblk = (cnt[e] + 63) >> 6;
  if ((int)blockIdx.x >= nblk) return;
  const int tid = threadIdx.x, lane = tid & 63, wid = tid >> 6;
  const int base = offs[e] + blockIdx.x * 64;
  const int n0 = blockIdx.y * 128;
  const int wm = wid >> 1, wn = wid & 1;

  if (tid < 128) b1_s[tid] = b1[e * 256 + n0 + tid];

  int tk[2];
  #pragma unroll
  for (int c = 0; c < 2; ++c)
    tk[c] = tok_list[base + (wid * 2 + c) * 8 + (lane >> 3)];

  f32x4 acc[2][4];
  #pragma unroll
  for (int i = 0; i < 2; ++i)
    #pragma unroll
    for (int j = 0; j < 4; ++j) acc[i][j] = (f32x4){0.f, 0.f, 0.f, 0.f};

  const char* Bb = (const char*)w1t + ((size_t)e * 256 + n0) * 2048;
  const int cb = ((lane & 7) ^ ((lane >> 3) & 7)) * 16;   // swizzled source col
  for (int kt = 0; kt < 16; ++kt) {
    __syncthreads();
    {   // gather-stage A [64][64] swizzled
      char* l = (char*)As + wid * 2048;
      #pragma unroll
      for (int c = 0; c < 2; ++c)
        gld16((const char*)xb + (size_t)tk[c] * 2048 + kt * 128 + cb, l + c * 1024);
    }
    stage_tile_swz(Bs, Bb + kt * 128, 2048, wid, lane);
    __syncthreads();
    mma_64x128_swz(As, Bs, acc, wm, wn, lane);
  }

  #pragma unroll
  for (int mf = 0; mf < 2; ++mf)
    #pragma unroll
    for (int rr = 0; rr < 4; ++rr) {
      const int lt = wm * 32 + mf * 16 + ((lane >> 4) << 2) + rr;
      #pragma unroll
      for (int nf = 0; nf < 4; ++nf) {
        const int ln = wn * 64 + nf * 16 + (lane & 15);
        float u = acc[mf][nf][rr] + b1_s[ln];
        h_c[(size_t)(base + lt) * 256 + n0 + ln] = f2bf(gelu_exact(u));
      }
    }
}

// ---------------- pass B (compact, 512 thr, BM=128 BN=256, swizzled): o = h @ W2e + b2e ----------------
// grid (264, 4): x = padded compact 128-row tile via find_expert (offs 128-padded
// so tiles never span experts), y = 256-col n-tile. 8 waves 2x4, wave does 64x64.
__global__ __launch_bounds__(512) void moe_out_kernel(
    const u16* __restrict__ h_c, const u16* __restrict__ w2t,
    const float* __restrict__ b2, const int* __restrict__ cnt,
    const int* __restrict__ offs, u16* __restrict__ o_c) {
  __shared__ u16 As[128 * 64];    // 16 KB
  __shared__ u16 Bs[256 * 64];    // 32 KB
  const int tid = threadIdx.x, lane = tid & 63, wid = tid >> 6;
  const int base = blockIdx.x * 128;
  const int e = find_expert(offs, base);
  if (base >= offs[e] + ((cnt[e] + 127) & ~127)) return;
  const int n0 = blockIdx.y * 256;
  const int wm = wid >> 2, wn = wid & 3;
  const int r = lane & 15, kq = (lane >> 4) * 8;

  f32x4 acc[4][4];
  #pragma unroll
  for (int i = 0; i < 4; ++i)
    #pragma unroll
    for (int j = 0; j < 4; ++j) acc[i][j] = (f32x4){0.f, 0.f, 0.f, 0.f};

  const char* Ab = (const char*)h_c + (size_t)base * 512;
  const char* Bb = (const char*)w2t + ((size_t)e * D_DIM + n0) * 512;
  #pragma unroll 1
  for (int kt = 0; kt < 4; ++kt) {
    __syncthreads();
    stage_a128_8w(As, Ab + kt * 128, 512, wid, lane);
    stage_b256_8w(Bs, Bb + kt * 128, 512, wid, lane);
    __syncthreads();
    #pragma unroll
    for (int ks = 0; ks < 2; ++ks) {
      const int col = ks * 32 + kq;
      bf16x8 a[4], b[4];
      #pragma unroll
      for (int mf = 0; mf < 4; ++mf)
        a[mf] = rd_swz(As, wm * 64 + mf * 16 + r, col);
      #pragma unroll
      for (int nf = 0; nf < 4; ++nf)
        b[nf] = rd_swz(Bs, wn * 64 + nf * 16 + r, col);
      #pragma unroll
      for (int mf = 0; mf < 4; ++mf)
        #pragma unroll
        for (int nf = 0; nf < 4; ++nf)
          acc[mf][nf] = __builtin_amdgcn_mfma_f32_16x16x32_bf16(a[mf], b[nf], acc[mf][nf], 0, 0, 0);
    }
  }

  #pragma unroll
  for (int nf = 0; nf < 4; ++nf) {
    const int ln = wn * 64 + nf * 16 + (lane & 15);
    const float bv = b2[(size_t)e * 1024 + n0 + ln];
    #pragma unroll
    for (int mf = 0; mf < 4; ++mf)
      #pragma unroll
      for (int rr = 0; rr < 4; ++rr) {
        const int lt = wm * 64 + mf * 16 + ((lane >> 4) << 2) + rr;
        o_c[(size_t)(base + lt) * 1024 + n0 + ln] = f2bf(acc[mf][nf][rr] + bv);
      }
  }
}

// ---------------- gather: y[t] = g1*o[p1] + g2*o[p2] ----------------
__global__ __launch_bounds__(256) void gather_kernel(
    const u16* __restrict__ o_c, const int* __restrict__ pos1,
    const int* __restrict__ pos2, const float2* __restrict__ top_g,
    float* __restrict__ y) {
  const int t = blockIdx.x;
  const int p1 = pos1[t], p2 = pos2[t];
  const float2 g = top_g[t];
  const int c = threadIdx.x * 4;
  u16x4 a = *(const u16x4*)&o_c[(size_t)p1 * 1024 + c];
  u16x4 b = *(const u16x4*)&o_c[(size_t)p2 * 1024 + c];
  float4 o;
  o.x = g.x * bf2f(a.x) + g.y * bf2f(b.x);
  o.y = g.x * bf2f(a.y) + g.y * bf2f(b.y);
  o.z = g.x * bf2f(a.z) + g.y * bf2f(b.z);
  o.w = g.x * bf2f(a.w) + g.y * bf2f(b.w);
  *(float4*)&y[(size_t)t * 1024 + c] = o;
}

extern "C" void kernel_launch(void* const* d_in, const int* in_sizes, int n_in,
                              void* d_out, int out_size, void* d_ws, size_t ws_size,
                              hipStream_t stream) {
  (void)in_sizes; (void)n_in; (void)out_size; (void)ws_size;
  const float* x   = (const float*)d_in[0];
  const float* wg1 = (const float*)d_in[1];
  const float* bg1 = (const float*)d_in[2];
  const float* wg2 = (const float*)d_in[3];
  const float* bg2 = (const float*)d_in[4];
  const float* w1  = (const float*)d_in[5];
  const float* b1  = (const float*)d_in[6];
  const float* w2  = (const float*)d_in[7];
  const float* b2  = (const float*)d_in[8];
  float* y = (float*)d_out;

  char* ws = (char*)d_ws;
  u16* xb   = (u16*)(ws);                 // 33,554,432 B  (= x_hi; expert path input)
  u16* w1t  = (u16*)(ws + 33554432);      //  4,194,304 B
  u16* w2t  = (u16*)(ws + 37748736);      //  4,194,304 B
  char* M   = ws + 41943040;              // metadata block
  int*    cnt      = (int*)(M);                 // 32 B
  int*    offs     = (int*)(M + 64);            // 32 B
  int*    hist     = (int*)(M + 128);           // 2,048 B
  int*    cbase    = (int*)(M + 2304);          // 2,048 B
  int*    tok_list = (int*)(M + 4608);          // 135,168 B
  int*    top_i    = (int*)(M + 139776);        // 65,536 B
  float2* top_g    = (float2*)(M + 205312);     // 131,072 B
  int*    pos1     = (int*)(M + 336384);        // 65,536 B
  int*    pos2     = (int*)(M + 401920);        // 65,536 B
  u16* h_c = (u16*)(ws + 42467328);       // MAXP*256*2 = 17,301,504 B
  u16* o_c = (u16*)(ws + 59768832);       // MAXP*1024*2 = 69,206,016 B (ends 128,974,848)
  // Aliased onto o_c region (all dead before moe_out writes o_c):
  float* p_buf   = (float*)(ws + 59768832);          // [2][T][256] f32 = 33,554,432 B
  u16*   wg1t_hi = (u16*)(ws + 93323264);            // 524,288 B
  u16*   wg1t_lo = (u16*)(ws + 93847552);            // 524,288 B
  u16*   xl      = (u16*)(ws + 94371840);            // 33,554,432 B (ends 127,926,272)

  hipMemsetAsync(tok_list, 0, 135168, stream);  // pad slots -> token 0
  cvt_hilo_x_kernel<<<16384, 256, 0, stream>>>(x, xb, xl);
  transpose_cvt_kernel<<<dim3(32, 8, 8), 256, 0, stream>>>(w1, w1t, 1024, 256);
  transpose_cvt_kernel<<<dim3(8, 32, 8), 256, 0, stream>>>(w2, w2t, 256, 1024);
  transpose_hilo_kernel<<<dim3(32, 8), 256, 0, stream>>>(wg1, wg1t_hi, wg1t_lo, 1024, 256);
  gating_mfma_kernel<<<dim3(256, 2, 2), 256, 0, stream>>>(xb, xl, wg1t_hi, wg1t_lo, p_buf);
  gating_p2_kernel<<<512, 256, 0, stream>>>(p_buf, bg1, wg2, bg2, top_i, top_g);
  hist_kernel<<<64, 256, 0, stream>>>(top_i, hist);
  scan_kernel<<<1, 64, 0, stream>>>(hist, cnt, offs, cbase);
  fill_kernel<<<64, 256, 0, stream>>>(top_i, cbase, tok_list, pos1, pos2);
  expert_h_kernel<<<dim3(256, 2, 8), 256, 0, stream>>>(xb, w1t, b1, tok_list, cnt, offs, h_c);
  moe_out_kernel<<<dim3(264, 4), 512, 0, stream>>>(h_c, w2t, b2, cnt, offs, o_c);
  gather_kernel<<<16384, 256, 0, stream>>>(o_c, pos1, pos2, top_g, y);
}